// Round 12
// baseline (367.392 us; speedup 1.0000x reference)
//
#include <hip/hip_runtime.h>

#define HH 64

// one-time: w2t[j*64+i] = w2[i*64+j]
static __global__ void k_prep_w2t(const float* __restrict__ w2, float* __restrict__ w2t){
  int t = blockIdx.x * 256 + threadIdx.x;   // 16 blocks x 256 = 4096
  w2t[t] = w2[(t & 63) * HH + (t >> 6)];
}

// ===================== pair-MLP core (LDS weights) ==========
// ~7.5k pts/us chip-wide, LDS-datapath-bound (8 ds_read_b128 + 2 swizzle
// per wave-j feeding 64 lane-FMAs).
__device__ __forceinline__ void mlp_pair(
    const float* __restrict__ sw1,   // LDS: x[64] y[64] z[64] b1[64]
    const float* __restrict__ sw2t,  // LDS: 4096
    const float* __restrict__ b2, const float* __restrict__ w3,
    const float* __restrict__ b3,
    float xA, float yA, float zA, float xB, float yB, float zB,
    float& outA, float& outB)
{
  const int ibase = ((threadIdx.x & 63) >> 5) * 32;
  float h1a[32], h1b[32];
  #pragma unroll
  for (int k = 0; k < 32; k += 4){
    const float4 wx = *(const float4*)&sw1[      ibase + k];
    const float4 wy = *(const float4*)&sw1[ 64 + ibase + k];
    const float4 wz = *(const float4*)&sw1[128 + ibase + k];
    const float4 bb = *(const float4*)&sw1[192 + ibase + k];
    h1a[k+0] = fmaxf(fmaf(xA,wx.x,fmaf(yA,wy.x,fmaf(zA,wz.x,bb.x))),0.f);
    h1a[k+1] = fmaxf(fmaf(xA,wx.y,fmaf(yA,wy.y,fmaf(zA,wz.y,bb.y))),0.f);
    h1a[k+2] = fmaxf(fmaf(xA,wx.z,fmaf(yA,wy.z,fmaf(zA,wz.z,bb.z))),0.f);
    h1a[k+3] = fmaxf(fmaf(xA,wx.w,fmaf(yA,wy.w,fmaf(zA,wz.w,bb.w))),0.f);
    h1b[k+0] = fmaxf(fmaf(xB,wx.x,fmaf(yB,wy.x,fmaf(zB,wz.x,bb.x))),0.f);
    h1b[k+1] = fmaxf(fmaf(xB,wx.y,fmaf(yB,wy.y,fmaf(zB,wz.y,bb.y))),0.f);
    h1b[k+2] = fmaxf(fmaf(xB,wx.z,fmaf(yB,wy.z,fmaf(zB,wz.z,bb.z))),0.f);
    h1b[k+3] = fmaxf(fmaf(xB,wx.w,fmaf(yB,wy.w,fmaf(zB,wz.w,bb.w))),0.f);
  }
  float oa = b3[0], ob = oa;
  #pragma unroll 1
  for (int j = 0; j < HH; ++j){
    const float4* wrow = (const float4*)&sw2t[j*HH + ibase];
    float a0 = 0.f, a1 = 0.f, c0 = 0.f, c1 = 0.f;
    #pragma unroll
    for (int q = 0; q < 8; q += 2){
      const float4 w0 = wrow[q];
      const float4 w1q = wrow[q+1];
      a0 = fmaf(h1a[4*q+0], w0.x, a0);
      a0 = fmaf(h1a[4*q+1], w0.y, a0);
      a0 = fmaf(h1a[4*q+2], w0.z, a0);
      a0 = fmaf(h1a[4*q+3], w0.w, a0);
      a1 = fmaf(h1a[4*q+4], w1q.x, a1);
      a1 = fmaf(h1a[4*q+5], w1q.y, a1);
      a1 = fmaf(h1a[4*q+6], w1q.z, a1);
      a1 = fmaf(h1a[4*q+7], w1q.w, a1);
      c0 = fmaf(h1b[4*q+0], w0.x, c0);
      c0 = fmaf(h1b[4*q+1], w0.y, c0);
      c0 = fmaf(h1b[4*q+2], w0.z, c0);
      c0 = fmaf(h1b[4*q+3], w0.w, c0);
      c1 = fmaf(h1b[4*q+4], w1q.x, c1);
      c1 = fmaf(h1b[4*q+5], w1q.y, c1);
      c1 = fmaf(h1b[4*q+6], w1q.z, c1);
      c1 = fmaf(h1b[4*q+7], w1q.w, c1);
    }
    float accA = a0 + a1, accB = c0 + c1;
    accA += __shfl_xor(accA, 32);
    accB += __shfl_xor(accB, 32);
    const float bj = b2[j], wj = w3[j];
    oa = fmaf(fmaxf(accA + bj, 0.f), wj, oa);
    ob = fmaf(fmaxf(accB + bj, 0.f), wj, ob);
  }
  outA = 1.f / (1.f + expf(-oa));
  outB = 1.f / (1.f + expf(-ob));
}

#define STAGE_WEIGHTS(SW1, SW2T)                                   \
  {                                                                \
    const int t0 = threadIdx.x;                                    \
    if (t0 < 3*HH) SW1[t0] = w1[t0];                               \
    else SW1[t0] = b1[t0 - 3*HH];                                  \
    const float4* s4 = (const float4*)w2t;                         \
    float4* d4 = (float4*)SW2T;                                    \
    for (int i4 = t0; i4 < HH*HH/4; i4 += 256) d4[i4] = s4[i4];    \
    __syncthreads();                                               \
  }

__device__ __forceinline__ void eval_point_coords(
    unsigned int pid, int R, int s, float& x, float& y, float& z)
{
  const float inv129x2 = 2.0f / 129.0f;
  unsigned int c = pid % (unsigned int)R, r = pid / (unsigned int)R;
  x = ((float)(c * (unsigned int)s) + 0.5f) * inv129x2 - 1.0f;
  y = ((float)((r % (unsigned int)R) * (unsigned int)s) + 0.5f) * inv129x2 - 1.0f;
  z = ((float)((r / (unsigned int)R) * (unsigned int)s) + 0.5f) * inv129x2 - 1.0f;
}

// ---------------- merged dense pair eval: L17 (blocks 0..19) + L33 ----------
static __global__ __launch_bounds__(256)
__attribute__((amdgpu_waves_per_eu(4,4)))
void k_eval_dual(
    const float* __restrict__ w1, const float* __restrict__ b1,
    const float* __restrict__ w2t, const float* __restrict__ b2,
    const float* __restrict__ w3, const float* __restrict__ b3,
    float* __restrict__ out17, unsigned char* __restrict__ calc17,
    float* __restrict__ out33)
{
  __shared__ float sw1[4*HH];
  __shared__ float sw2t[HH*HH];
  STAGE_WEIGHTS(sw1, sw2t);
  int R, s; float* outp; unsigned char* c1; unsigned int blk;
  if (blockIdx.x < 20){ R = 17; s = 8; outp = out17; c1 = calc17; blk = blockIdx.x; }
  else                { R = 33; s = 4; outp = out33; c1 = nullptr; blk = blockIdx.x - 20; }
  const unsigned int n = (unsigned int)R * (unsigned int)R * (unsigned int)R;
  const int lane = threadIdx.x & 63;
  const int wid = threadIdx.x >> 6;
  const unsigned int base = blk * 256u + (unsigned int)(wid * 64 + (lane & 31));
  const unsigned int pidA = base < n ? base : (n - 1u);
  const unsigned int pB = base + 32u;
  const unsigned int pidB = pB < n ? pB : (n - 1u);
  float xA,yA,zA,xB,yB,zB;
  eval_point_coords(pidA, R, s, xA, yA, zA);
  eval_point_coords(pidB, R, s, xB, yB, zB);
  float oA, oB;
  mlp_pair(sw1, sw2t, b2, w3, b3, xA, yA, zA, xB, yB, zB, oA, oB);
  if (lane < 32){
    if (base < n){ outp[pidA] = oA; if (c1) c1[pidA] = 1; }
    if (pB < n)  { outp[pidB] = oB; if (c1) c1[pidB] = 1; }
  }
}

// ---- upsample + seed + calc + init occ_out=occ_i + zero conf arrays ----
static __global__ __launch_bounds__(256) void k_resize_b0(
    const float* __restrict__ prev,
    const unsigned char* __restrict__ calc_prev,
    float* __restrict__ occ_i, float* __restrict__ occ_out,
    unsigned char* __restrict__ bnd0, unsigned char* __restrict__ calc_out,
    unsigned char* __restrict__ confA, unsigned char* __restrict__ confB,
    int R, int Rp)
{
  const unsigned int n = (unsigned int)R * (unsigned int)R * (unsigned int)R;
  unsigned int gid = blockIdx.x * 256u + threadIdx.x;
  if (gid >= n) return;
  int c = (int)(gid % (unsigned int)R);
  unsigned int r = gid / (unsigned int)R;
  int b = (int)(r % (unsigned int)R);
  int a = (int)(r / (unsigned int)R);
  int a0 = a >> 1, da = a & 1;
  int b0i = b >> 1, db = b & 1;
  int c0 = c >> 1, dc = c & 1;
  float sum = 0.0f;
  int cnt = 0;
  const int tot = (da + 1) * (db + 1) * (dc + 1);
  for (int dz = 0; dz <= da; ++dz)
    for (int dy = 0; dy <= db; ++dy)
      for (int dx = 0; dx <= dc; ++dx){
        float v = prev[((unsigned int)(a0 + dz) * (unsigned int)Rp + (unsigned int)(b0i + dy)) * (unsigned int)Rp + (unsigned int)(c0 + dx)];
        sum += v;
        cnt += (v > 0.5f) ? 1 : 0;
      }
  float oi = sum / (float)tot;
  occ_i[gid] = oi;
  occ_out[gid] = oi;
  bnd0[gid] = (cnt > 0 && cnt < tot) ? 1 : 0;
  calc_out[gid] = ((da | db | dc) == 0)
      ? calc_prev[((unsigned int)a0 * (unsigned int)Rp + (unsigned int)b0i) * (unsigned int)Rp + (unsigned int)c0]
      : (unsigned char)0;
  confA[gid] = 0; confB[gid] = 0;
}

// ---- dense variant with mism + occ_out init (R=33 path) ----
static __global__ __launch_bounds__(256) void k_resize_boundary(
    const float* __restrict__ prev, const float* __restrict__ occ_true,
    const unsigned char* __restrict__ calc_prev,
    float* __restrict__ occ_i, float* __restrict__ occ_out,
    unsigned char* __restrict__ bnd0,
    unsigned char* __restrict__ mism, unsigned char* __restrict__ calc_out,
    int R, int Rp)
{
  const unsigned int n = (unsigned int)R * (unsigned int)R * (unsigned int)R;
  unsigned int gid = blockIdx.x * 256u + threadIdx.x;
  if (gid >= n) return;
  int c = (int)(gid % (unsigned int)R);
  unsigned int r = gid / (unsigned int)R;
  int b = (int)(r % (unsigned int)R);
  int a = (int)(r / (unsigned int)R);
  int a0 = a >> 1, da = a & 1;
  int b0i = b >> 1, db = b & 1;
  int c0 = c >> 1, dc = c & 1;
  float sum = 0.0f;
  int cnt = 0;
  const int tot = (da + 1) * (db + 1) * (dc + 1);
  for (int dz = 0; dz <= da; ++dz)
    for (int dy = 0; dy <= db; ++dy)
      for (int dx = 0; dx <= dc; ++dx){
        float v = prev[((unsigned int)(a0 + dz) * (unsigned int)Rp + (unsigned int)(b0i + dy)) * (unsigned int)Rp + (unsigned int)(c0 + dx)];
        sum += v;
        cnt += (v > 0.5f) ? 1 : 0;
      }
  float oi = sum / (float)tot;
  occ_i[gid] = oi;
  occ_out[gid] = oi;
  bnd0[gid] = (cnt > 0 && cnt < tot) ? 1 : 0;
  mism[gid] = ((oi - 0.5f) * (occ_true[gid] - 0.5f) < 0.0f) ? 1 : 0;
  calc_out[gid] = ((da | db | dc) == 0)
      ? calc_prev[((unsigned int)a0 * (unsigned int)Rp + (unsigned int)b0i) * (unsigned int)Rp + (unsigned int)c0]
      : (unsigned char)0;
}

// ==== FUSED: tiled 7^3 dilation -> tile candidate list -> pair-MLP eval ====
// One block per 8^3 tile (256 threads). Replaces dil7_tiled + scan + scatter
// + eval_sparse (3 dispatch gaps + global index round-trip). Writes per-tile
// candidate list (tlist[tile*512+k]) + count for the dilate-step kernels.
// Weights staged only in non-empty tiles.
static __global__ __launch_bounds__(256)
__attribute__((amdgpu_waves_per_eu(4,4)))
void k_dil7_eval(
    const float* __restrict__ w1, const float* __restrict__ b1,
    const float* __restrict__ w2t, const float* __restrict__ b2,
    const float* __restrict__ w3, const float* __restrict__ b3,
    const unsigned char* __restrict__ b0,
    const float* __restrict__ occ_i,
    float* __restrict__ out, unsigned char* __restrict__ mism,
    int* __restrict__ tlist, unsigned int* __restrict__ tcnt,
    int R, int T, int s)
{
  __shared__ unsigned char s0[14*14*14];
  __shared__ unsigned char s1[14*14*8];
  __shared__ unsigned char s2[14*8*8];
  __shared__ int lidx[512];
  __shared__ unsigned int wb[8];
  __shared__ unsigned int lcnt;
  __shared__ float sw1[4*HH];
  __shared__ float sw2t[HH*HH];

  const int tile = blockIdx.x;
  const int tz = tile / (T*T), ty = (tile / T) % T, tx = tile % T;
  const int bz = tz*8 - 3, by = ty*8 - 3, bx = tx*8 - 3;
  const int t = threadIdx.x;

  // stage b0 halo (14^3)
  for (int i = t; i < 2744; i += 256){
    int lz = i / 196, rr = i % 196, ly = rr / 14, lx = rr % 14;
    int gz = bz + lz, gy = by + ly, gx = bx + lx;
    unsigned char v = 0;
    if (gz >= 0 && gz < R && gy >= 0 && gy < R && gx >= 0 && gx < R)
      v = b0[((unsigned int)gz * (unsigned int)R + (unsigned int)gy) * (unsigned int)R + (unsigned int)gx];
    s0[i] = v;
  }
  __syncthreads();
  // x-pass -> s1 [z14][y14][x8]
  for (int i = t; i < 1568; i += 256){
    int lz = i / 112, rr = i % 112, ly = rr / 8, lx = rr % 8;
    const unsigned char* p = &s0[lz*196 + ly*14 + lx];
    s1[i] = (unsigned char)(p[0]|p[1]|p[2]|p[3]|p[4]|p[5]|p[6]);
  }
  __syncthreads();
  // y-pass -> s2 [z14][y8][x8]
  for (int i = t; i < 896; i += 256){
    int lz = i / 64, rr = i % 64, ly = rr / 8, lx = rr % 8;
    const unsigned char* p = &s1[lz*112 + ly*8 + lx];
    s2[i] = (unsigned char)(p[0]|p[8]|p[16]|p[24]|p[32]|p[40]|p[48]);
  }
  __syncthreads();
  // z-pass: 512 core cells, 2 per thread; candidate preds + gids
  int c0i = t, c1i = t + 256;
  int m0, m1, g0, g1;
  bool p0, p1;
  {
    int lz = c0i >> 6, ly = (c0i >> 3) & 7, lx = c0i & 7;
    const unsigned char* p = &s2[lz*64 + ly*8 + lx];
    m0 = p[0]|p[64]|p[128]|p[192]|p[256]|p[320]|p[384];
    int gz = tz*8 + lz, gy = ty*8 + ly, gx = tx*8 + lx;
    bool inb = (gz < R) && (gy < R) && (gx < R);
    g0 = inb ? (int)(((unsigned int)gz * (unsigned int)R + (unsigned int)gy) * (unsigned int)R + (unsigned int)gx) : 0;
    p0 = inb && m0;
  }
  {
    int lz = c1i >> 6, ly = (c1i >> 3) & 7, lx = c1i & 7;
    const unsigned char* p = &s2[lz*64 + ly*8 + lx];
    m1 = p[0]|p[64]|p[128]|p[192]|p[256]|p[320]|p[384];
    int gz = tz*8 + lz, gy = ty*8 + ly, gx = tx*8 + lx;
    bool inb = (gz < R) && (gy < R) && (gx < R);
    g1 = inb ? (int)(((unsigned int)gz * (unsigned int)R + (unsigned int)gy) * (unsigned int)R + (unsigned int)gx) : 0;
    p1 = inb && m1;
  }
  unsigned long long bm0 = __ballot(p0);
  unsigned long long bm1 = __ballot(p1);
  const int w = t >> 6, lane = t & 63;
  if (lane == 0){ wb[w] = (unsigned int)__popcll(bm0); wb[4+w] = (unsigned int)__popcll(bm1); }
  __syncthreads();
  if (t == 0){
    unsigned int run = 0;
    for (int k = 0; k < 8; ++k){ unsigned int v = wb[k]; wb[k] = run; run += v; }
    lcnt = run;
    tcnt[tile] = run;
  }
  __syncthreads();
  if (p0){
    unsigned int pos = wb[w] + (unsigned int)__popcll(bm0 & ((1ull << lane) - 1ull));
    lidx[pos] = g0; tlist[(unsigned int)tile * 512u + pos] = g0;
  }
  if (p1){
    unsigned int pos = wb[4+w] + (unsigned int)__popcll(bm1 & ((1ull << lane) - 1ull));
    lidx[pos] = g1; tlist[(unsigned int)tile * 512u + pos] = g1;
  }
  __syncthreads();
  const unsigned int count = lcnt;
  if (count == 0) return;               // block-uniform

  STAGE_WEIGHTS(sw1, sw2t);
  const int wid = w;
  for (unsigned int base = 0; base < count; base += 256u){
    unsigned int slotA = base + (unsigned int)(wid * 64 + (lane & 31));
    unsigned int slotB = slotA + 32u;
    bool vA = slotA < count, vB = slotB < count;
    unsigned int pidA = (unsigned int)lidx[vA ? slotA : 0];
    unsigned int pidB = (unsigned int)lidx[vB ? slotB : 0];
    float xA,yA,zA,xB,yB,zB;
    eval_point_coords(pidA, R, s, xA, yA, zA);
    eval_point_coords(pidB, R, s, xB, yB, zB);
    float oA, oB;
    mlp_pair(sw1, sw2t, b2, w3, b3, xA, yA, zA, xB, yB, zB, oA, oB);
    if (lane < 32){
      if (vA){
        out[pidA] = oA;
        mism[pidA] = ((occ_i[pidA] - 0.5f) * (oA - 0.5f) < 0.0f) ? (unsigned char)1 : (unsigned char)0;
      }
      if (vB){
        out[pidB] = oB;
        mism[pidB] = ((occ_i[pidB] - 0.5f) * (oB - 0.5f) < 0.0f) ? (unsigned char)1 : (unsigned char)0;
      }
    }
    __syncthreads();   // lidx stable; cheap (count<=512 -> at most 2 iters)
  }
}

// ---- per-tile-list dilate step; commits occ_true at calc-flip ----
static __global__ __launch_bounds__(256) void k_dilate_tile(
    const int* __restrict__ tlist, const unsigned int* __restrict__ tcnt,
    const unsigned char* __restrict__ src, const unsigned char* __restrict__ mism,
    unsigned char* __restrict__ calc, unsigned char* __restrict__ conf_out,
    int R, const float* __restrict__ occ_true, float* __restrict__ occ_out,
    unsigned int n)
{
  unsigned int cnt = tcnt[blockIdx.x];
  if (cnt > 512u) cnt = 512u;         // stale-ws guard (profiling replay)
  if (cnt == 0) return;
  const int* lst = &tlist[(unsigned int)blockIdx.x * 512u];
  for (unsigned int k = threadIdx.x; k < cnt; k += 256u){
    int gid = lst[k];
    if ((unsigned int)gid >= n) continue;   // stale-ws guard
    int c = gid % R;
    int r = gid / R;
    int b = r % R;
    int a = r / R;
    int m = 0;
    for (int dz = -1; dz <= 1; ++dz){
      int az = a + dz; if (az < 0 || az >= R) continue;
      for (int dy = -1; dy <= 1; ++dy){
        int by = b + dy; if (by < 0 || by >= R) continue;
        for (int dx = -1; dx <= 1; ++dx){
          int cx = c + dx; if (cx < 0 || cx >= R) continue;
          m |= src[(az * R + by) * R + cx];
        }
      }
    }
    unsigned char nb = (m && !calc[gid]) ? (unsigned char)1 : (unsigned char)0;
    conf_out[gid] = (nb && mism[gid]) ? (unsigned char)1 : (unsigned char)0;
    if (nb){
      calc[gid] = 1;
      occ_out[gid] = occ_true[gid];
    }
  }
}

// ---- fused 3-step dilate/conflict, tiled in LDS — R=33 ONLY (125 tiles) ----
static __global__ __launch_bounds__(512) void k_dilate3_tiled(
    const unsigned char* __restrict__ b0,
    const unsigned char* __restrict__ mism,
    unsigned char* __restrict__ calc,
    const float* __restrict__ occ_true,
    float* __restrict__ occ_out,
    int R, int T)
{
  __shared__ unsigned char sC[14*14*14];
  __shared__ unsigned char sD[14*14*14];
  __shared__ unsigned char sK[14*14*14];
  __shared__ unsigned char sM[14*14*14];
  __shared__ int s_any;
  const int tile = blockIdx.x;
  const int tz = tile / (T*T), ty = (tile / T) % T, tx = tile % T;
  const int bz = tz*8 - 3, by = ty*8 - 3, bx = tx*8 - 3;
  const int t = threadIdx.x;
  if (t == 0) s_any = 0;
  __syncthreads();
  int any = 0;
  for (int i = t; i < 2744; i += 512){
    int lz = i / 196, rr = i % 196, ly = rr / 14, lx = rr % 14;
    int gz = bz + lz, gy = by + ly, gx = bx + lx;
    bool in = (gz >= 0 && gz < R && gy >= 0 && gy < R && gx >= 0 && gx < R);
    unsigned int g = in ? (((unsigned int)gz * (unsigned int)R + (unsigned int)gy) * (unsigned int)R + (unsigned int)gx) : 0u;
    unsigned char v0 = in ? b0[g] : (unsigned char)0;
    sC[i] = v0; any |= v0;
    sK[i] = in ? calc[g] : (unsigned char)1;
    sM[i] = in ? mism[g] : (unsigned char)0;
  }
  if (any) s_any = 1;
  __syncthreads();
  if (!s_any) return;

  const int clz = 3 + (t >> 6), cly = 3 + ((t >> 3) & 7), clx = 3 + (t & 7);
  const int cp = clz*196 + cly*14 + clx;
  const unsigned char calc0 = sK[cp];
  __syncthreads();

  for (int i = t; i < 1728; i += 512){
    int lz = i / 144 + 1, rr = i % 144, ly = rr / 12 + 1, lx = rr % 12 + 1;
    int p = lz*196 + ly*14 + lx;
    int m = 0;
    #pragma unroll
    for (int dz = -1; dz <= 1; ++dz)
      #pragma unroll
      for (int dy = -1; dy <= 1; ++dy)
        #pragma unroll
        for (int dx = -1; dx <= 1; ++dx)
          m |= sC[p + dz*196 + dy*14 + dx];
    unsigned char nb = (m && !sK[p]) ? (unsigned char)1 : (unsigned char)0;
    sD[p] = (nb && sM[p]) ? (unsigned char)1 : (unsigned char)0;
    if (nb) sK[p] = 1;
  }
  __syncthreads();
  for (int i = t; i < 1000; i += 512){
    int lz = i / 100 + 2, rr = i % 100, ly = rr / 10 + 2, lx = rr % 10 + 2;
    int p = lz*196 + ly*14 + lx;
    int m = 0;
    #pragma unroll
    for (int dz = -1; dz <= 1; ++dz)
      #pragma unroll
      for (int dy = -1; dy <= 1; ++dy)
        #pragma unroll
        for (int dx = -1; dx <= 1; ++dx)
          m |= sD[p + dz*196 + dy*14 + dx];
    unsigned char nb = (m && !sK[p]) ? (unsigned char)1 : (unsigned char)0;
    sC[p] = (nb && sM[p]) ? (unsigned char)1 : (unsigned char)0;
    if (nb) sK[p] = 1;
  }
  __syncthreads();
  {
    int m = 0;
    #pragma unroll
    for (int dz = -1; dz <= 1; ++dz)
      #pragma unroll
      for (int dy = -1; dy <= 1; ++dy)
        #pragma unroll
        for (int dx = -1; dx <= 1; ++dx)
          m |= sC[cp + dz*196 + dy*14 + dx];
    if (m && !sK[cp]) sK[cp] = 1;
  }
  int gz = tz*8 + (clz - 3), gy = ty*8 + (cly - 3), gx = tx*8 + (clx - 3);
  if (gz < R && gy < R && gx < R){
    unsigned int g = ((unsigned int)gz * (unsigned int)R + (unsigned int)gy) * (unsigned int)R + (unsigned int)gx;
    unsigned char cf = sK[cp];
    calc[g] = cf;
    if (cf && !calc0) occ_out[g] = occ_true[g];
  }
}

extern "C" void kernel_launch(void* const* d_in, const int* in_sizes, int n_in,
                              void* d_out, int out_size, void* d_ws, size_t ws_size,
                              hipStream_t stream)
{
  const float* w1 = (const float*)d_in[0];
  const float* b1 = (const float*)d_in[1];
  const float* w2 = (const float*)d_in[2];
  const float* b2 = (const float*)d_in[3];
  const float* w3 = (const float*)d_in[4];
  const float* b3 = (const float*)d_in[5];
  float* out = (float*)d_out;

  const int NF = 129 * 129 * 129;  // 2146689
  const int NP = 65 * 65 * 65;
  const int MAXTILES = 17 * 17 * 17;  // 4913
  char* ws = (char*)d_ws;
  size_t off = 0;
  auto alloc = [&](size_t bytes) -> void* {
    void* p = (void*)(ws + off);
    off += (bytes + 255) & ~(size_t)255;
    return p;
  };
  float* f_true  = (float*)alloc((size_t)NF * 4);
  float* f_occi  = (float*)alloc((size_t)NF * 4);
  float* f_prevA = (float*)alloc((size_t)NP * 4);
  float* f_prevB = (float*)alloc((size_t)NP * 4);
  float* f_w2t   = (float*)alloc((size_t)HH * HH * 4);
  int*   tlist   = (int*)alloc((size_t)MAXTILES * 512 * 4);
  unsigned int* tcnt = (unsigned int*)alloc((size_t)MAXTILES * 4);
  unsigned char* b_b0    = (unsigned char*)alloc(NF);
  unsigned char* b_mism  = (unsigned char*)alloc(NF);
  unsigned char* b_confA = (unsigned char*)alloc(NF);
  unsigned char* b_confB = (unsigned char*)alloc(NF);
  unsigned char* b_calcA = (unsigned char*)alloc(NF);
  unsigned char* b_calcB = (unsigned char*)alloc(NF);
  (void)ws_size;

  k_prep_w2t<<<16, 256, 0, stream>>>(w2, f_w2t);

  // L17 + L33 dense evals in one dispatch (independent)
  k_eval_dual<<<20 + 141, 256, 0, stream>>>(w1, b1, f_w2t, b2, w3, b3,
                                            f_prevA, b_calcA, f_true);

  // ---- L33 (dense) ----
  {
    int R = 33, Rp = 17;
    unsigned int n = (unsigned int)R * R * R;
    int blocks = (int)((n + 255u) / 256u);
    int T = (R + 7) / 8;
    k_resize_boundary<<<blocks, 256, 0, stream>>>(f_prevA, f_true, b_calcA,
        f_occi, f_prevB, b_b0, b_mism, b_calcB, R, Rp);
    k_dilate3_tiled<<<T*T*T, 512, 0, stream>>>(b_b0, b_mism, b_calcB, f_true, f_prevB, R, T);
  }

  // ---- L65 (sparse) ----
  {
    int R = 65, Rp = 33, s = 2;
    unsigned int n = (unsigned int)R * R * R;
    int blocks = (int)((n + 255u) / 256u);
    int T = (R + 7) / 8;               // 9
    int tb = T * T * T;                // 729
    k_resize_b0<<<blocks, 256, 0, stream>>>(f_prevB, b_calcB, f_occi, f_prevA,
        b_b0, b_calcA, b_confA, b_confB, R, Rp);
    k_dil7_eval<<<tb, 256, 0, stream>>>(w1, b1, f_w2t, b2, w3, b3,
        b_b0, f_occi, f_true, b_mism, tlist, tcnt, R, T, s);
    k_dilate_tile<<<tb, 256, 0, stream>>>(tlist, tcnt, b_b0,    b_mism, b_calcA, b_confA, R, f_true, f_prevA, n);
    k_dilate_tile<<<tb, 256, 0, stream>>>(tlist, tcnt, b_confA, b_mism, b_calcA, b_confB, R, f_true, f_prevA, n);
    k_dilate_tile<<<tb, 256, 0, stream>>>(tlist, tcnt, b_confB, b_mism, b_calcA, b_confA, R, f_true, f_prevA, n);
  }

  // ---- L129 (sparse) ----
  {
    int R = 129, Rp = 65, s = 1;
    unsigned int n = (unsigned int)R * R * R;
    int blocks = (int)((n + 255u) / 256u);
    int T = (R + 7) / 8;               // 17
    int tb = T * T * T;                // 4913
    k_resize_b0<<<blocks, 256, 0, stream>>>(f_prevA, b_calcA, f_occi, out,
        b_b0, b_calcB, b_confA, b_confB, R, Rp);
    k_dil7_eval<<<tb, 256, 0, stream>>>(w1, b1, f_w2t, b2, w3, b3,
        b_b0, f_occi, f_true, b_mism, tlist, tcnt, R, T, s);
    k_dilate_tile<<<tb, 256, 0, stream>>>(tlist, tcnt, b_b0,    b_mism, b_calcB, b_confA, R, f_true, out, n);
    k_dilate_tile<<<tb, 256, 0, stream>>>(tlist, tcnt, b_confA, b_mism, b_calcB, b_confB, R, f_true, out, n);
    k_dilate_tile<<<tb, 256, 0, stream>>>(tlist, tcnt, b_confB, b_mism, b_calcB, b_confA, R, f_true, out, n);
  }
  (void)in_sizes; (void)n_in; (void)out_size;
}